// Round 15
// baseline (139.331 us; speedup 1.0000x reference)
//
#include <hip/hip_runtime.h>
#include <hip/hip_bf16.h>

// MultiLatentAttention on MI355X.
// causal mask t<=l with L=64 => attention only over first 64 tokens.
// out[b] = softmax_groups(x@Wg) @ M[b],  M built from attn_out and Wp (MFMA).
// Round 15: kv projection folded INTO attn_mt (per-block MFMA projection of its
// own 64-row K/V slice) — removes the gemm_kv launch, the 16MB kvp round-trip,
// and the d_out-scratch hack. Both big GEMMs stay on the proven 256^2 2-phase
// kernel (48.7us each; 6 schedule variants bracketed it).

typedef __attribute__((ext_vector_type(8))) short bf16x8;
typedef __attribute__((ext_vector_type(4))) float f32x4;
typedef __attribute__((ext_vector_type(4))) unsigned short us4;

__device__ __forceinline__ void gll16(const void* g, void* l) {
  __builtin_amdgcn_global_load_lds((const __attribute__((address_space(1))) void*)g,
                                   (__attribute__((address_space(3))) void*)l, 16, 0, 0);
}

// ---------------- prep: x->bf16 (blocks 0..2047) + 4 weight transposes (2048..6143) ----------
__global__ __launch_bounds__(256)
void prep_kernel(const float* __restrict__ x, __hip_bfloat16* __restrict__ xb,
                 const float* __restrict__ Wg, const float* __restrict__ Wk,
                 const float* __restrict__ Wv, const float* __restrict__ Wp,
                 __hip_bfloat16* __restrict__ WgT, __hip_bfloat16* __restrict__ WkT,
                 __hip_bfloat16* __restrict__ WvT, __hip_bfloat16* __restrict__ WpT) {
  const int bid = blockIdx.x, tid = threadIdx.x;
  if (bid < 2048) {
    const int stride = 2048 * 256;
    for (int i = bid * 256 + tid; i < 4194304; i += stride) {
      float4 f = reinterpret_cast<const float4*>(x)[i];
      union { __hip_bfloat16 h[4]; us4 v; } u;
      u.h[0] = __float2bfloat16(f.x);
      u.h[1] = __float2bfloat16(f.y);
      u.h[2] = __float2bfloat16(f.z);
      u.h[3] = __float2bfloat16(f.w);
      reinterpret_cast<us4*>(xb)[i] = u.v;
    }
  } else {
    const int t = bid - 2048;
    const int z = t >> 10, rem = t & 1023;
    const float* W = (z == 0) ? Wg : ((z == 1) ? Wk : ((z == 2) ? Wv : Wp));
    __hip_bfloat16* Wt = (z == 0) ? WgT : ((z == 1) ? WkT : ((z == 2) ? WvT : WpT));
    __shared__ float tile[32][33];
    const int bx = (rem & 31) * 32, by = (rem >> 5) * 32;
    const int tx = tid & 31, ty = tid >> 5;  // 32x8
    #pragma unroll
    for (int j = 0; j < 32; j += 8)
      tile[ty + j][tx] = W[(size_t)(by + ty + j) * 1024 + bx + tx];
    __syncthreads();
    #pragma unroll
    for (int j = 0; j < 32; j += 8)
      Wt[(size_t)(bx + ty + j) * 1024 + by + tx] = __float2bfloat16(tile[tx][ty + j]);
  }
}

// ---------------- 256x256 2-phase pipelined bf16 GEMM (proven ~48.8us) ----------------
// 8 waves (2Mx4N), BK=64, double-buffered 128KiB LDS. LDS swizzle: 16B-chunk ^= (row&7),
// pre-swizzled on the GLOBAL source (gll16 dest linear), applied on fragment reads.
// EPI=0: fp32 store. EPI=1: per-64-column-group softmax, bf16 store (gates).
template <int EPI>
__global__ __launch_bounds__(512, 2)
void gemm256(const __hip_bfloat16* __restrict__ A, const __hip_bfloat16* __restrict__ Bt,
             void* __restrict__ Cv, int K, int ldc,
             long long astride, long long bstride, long long cstride) {
  __shared__ __align__(16) unsigned short SA[2][256 * 64];
  __shared__ __align__(16) unsigned short SB[2][256 * 64];
  const int tid = threadIdx.x;
  const int lane = tid & 63;
  const int w = tid >> 6;            // wave 0..7
  const int wm = w >> 2, wn = w & 3; // 2x4 wave grid; per-wave out = 128x64
  const int lr = lane & 15, lk = lane >> 4;
  const int m0 = blockIdx.x * 256, n0 = blockIdx.y * 256;
  const long long b = blockIdx.z;
  const __hip_bfloat16* Ab = A + b * astride;
  const __hip_bfloat16* Bb = Bt + b * bstride;

  f32x4 acc[8][4] = {};

  const int NT = K >> 6;
  int buf = 0;

  auto STAGE = [&](int bsel, int kt) {
    #pragma unroll
    for (int r = 0; r < 4; ++r) {
      int c = r * 512 + tid;          // chunk 0..2047: row=c>>3, slot=c&7
      int row = c >> 3, slot = c & 7;
      int gch = slot ^ (row & 7);     // pre-swizzled global chunk
      gll16(Ab + (size_t)(m0 + row) * K + kt + gch * 8, (char*)&SA[bsel][0] + c * 16);
      gll16(Bb + (size_t)(n0 + row) * K + kt + gch * 8, (char*)&SB[bsel][0] + c * 16);
    }
  };

  STAGE(0, 0);
  __syncthreads();

  for (int t = 0; t < NT; ++t) {
    if (t + 1 < NT) STAGE(buf ^ 1, (t + 1) << 6);

    bf16x8 bfr[2][4];
    #pragma unroll
    for (int kk = 0; kk < 2; ++kk)
      #pragma unroll
      for (int ni = 0; ni < 4; ++ni) {
        int row = wn * 64 + ni * 16 + lr;
        int ch = (kk * 4 + lk) ^ (row & 7);
        bfr[kk][ni] = *(const bf16x8*)&SB[buf][row * 64 + ch * 8];
      }
    #pragma unroll
    for (int mi = 0; mi < 8; ++mi) {
      int row = wm * 128 + mi * 16 + lr;
      int ch0 = lk ^ (row & 7);
      int ch1 = (4 + lk) ^ (row & 7);
      bf16x8 a0 = *(const bf16x8*)&SA[buf][row * 64 + ch0 * 8];
      bf16x8 a1 = *(const bf16x8*)&SA[buf][row * 64 + ch1 * 8];
      #pragma unroll
      for (int ni = 0; ni < 4; ++ni)
        acc[mi][ni] = __builtin_amdgcn_mfma_f32_16x16x32_bf16(a0, bfr[0][ni], acc[mi][ni], 0, 0, 0);
      #pragma unroll
      for (int ni = 0; ni < 4; ++ni)
        acc[mi][ni] = __builtin_amdgcn_mfma_f32_16x16x32_bf16(a1, bfr[1][ni], acc[mi][ni], 0, 0, 0);
    }
    __syncthreads();
    buf ^= 1;
  }

  if (EPI == 0) {
    float* C = (float*)Cv + b * cstride;
    #pragma unroll
    for (int mi = 0; mi < 8; ++mi) {
      int r = m0 + wm * 128 + mi * 16 + lk * 4;
      #pragma unroll
      for (int ni = 0; ni < 4; ++ni) {
        int c = n0 + wn * 64 + ni * 16 + lr;
        #pragma unroll
        for (int jj = 0; jj < 4; ++jj)
          C[(size_t)(r + jj) * ldc + c] = acc[mi][ni][jj];
      }
    }
  } else {
    // Each wave's 64 columns = one softmax group (head h, l=0..63).
    __hip_bfloat16* C = (__hip_bfloat16*)Cv + b * cstride;
    #pragma unroll
    for (int mi = 0; mi < 8; ++mi) {
      #pragma unroll
      for (int jj = 0; jj < 4; ++jj) {
        float mx = -3.0e38f;
        #pragma unroll
        for (int ni = 0; ni < 4; ++ni) mx = fmaxf(mx, acc[mi][ni][jj]);
        mx = fmaxf(mx, __shfl_xor(mx, 1));
        mx = fmaxf(mx, __shfl_xor(mx, 2));
        mx = fmaxf(mx, __shfl_xor(mx, 4));
        mx = fmaxf(mx, __shfl_xor(mx, 8));
        float e[4];
        float s = 0.f;
        #pragma unroll
        for (int ni = 0; ni < 4; ++ni) { e[ni] = __expf(acc[mi][ni][jj] - mx); s += e[ni]; }
        s += __shfl_xor(s, 1);
        s += __shfl_xor(s, 2);
        s += __shfl_xor(s, 4);
        s += __shfl_xor(s, 8);
        float inv = 1.0f / s;
        int r = m0 + wm * 128 + mi * 16 + lk * 4 + jj;
        #pragma unroll
        for (int ni = 0; ni < 4; ++ni)
          C[(size_t)r * ldc + n0 + wn * 64 + ni * 16 + lr] = __float2bfloat16(e[ni] * inv);
      }
    }
  }
}

// ---------------- attn_mt v2: in-block kv projection + RoPE + attention + MFMA Mt -----------
// Grid (4 ct, 16 h, 4 b), 256 thr / 4 waves. Phases:
//  (0) stage WpT slice -> SW (gll16, overlaps phase 1 prologue)
//  (1) K/V projection: OUT[64 t][128 c] = x[b, t<64, :] @ [WkT_h | WvT_h]^T via MFMA,
//      A reg-staged fp32->bf16 (r7-proven pattern), B gll16 from WkvT; BK=32, 32 iters.
//      acc -> Ks (c<64) / Vs (c>=64) fp32 LDS.
//  (2) RoPE pass on Ks (interleaved pairs).
//  (3) attention: scores -> causal softmax -> PV -> SAo bf16 swizzled.
//  (4) Mt_slice[256c][64l] = SW @ SAo^T via MFMA; Mt[b][c][h*64+l] bf16.
__global__ __launch_bounds__(256)
void attn_mt(const float* __restrict__ X, const float* __restrict__ lq,
             const __hip_bfloat16* __restrict__ WkvT, const __hip_bfloat16* __restrict__ WpT,
             __hip_bfloat16* __restrict__ Mt) {
  const int ct = blockIdx.x, h = blockIdx.y, b = blockIdx.z;
  __shared__ __align__(16) unsigned short XA[64 * 32];    // x chunk bf16 [64 t][32 k]
  __shared__ __align__(16) unsigned short BB[128 * 32];   // [WkT_h|WvT_h] chunk [128 c][32 k]
  __shared__ __align__(16) unsigned short SW[256 * 64];   // WpT slice [256 c][64 d], swizzled
  __shared__ __align__(16) unsigned short SAo[64 * 64];   // ao bf16 [64 l][64 d], swizzled
  __shared__ float Ks[64][64];
  __shared__ float Vs[64][64];
  __shared__ float S[64][65];   // S[l][t]
  __shared__ float Pt[64][65];  // Pt[t][l]
  const int tid = threadIdx.x;
  const int lane = tid & 63;
  const int w = tid >> 6;            // wave 0..3
  const int lr = lane & 15, lk = lane >> 4;

  // ---- (0) stage WpT slice early ----
  #pragma unroll
  for (int j = 0; j < 8; ++j) {
    int c2 = j * 256 + tid;
    int row = c2 >> 3, slot = c2 & 7;
    int gch = slot ^ (row & 7);
    gll16(WpT + (size_t)(ct * 256 + row) * 1024 + h * 64 + gch * 8, (char*)SW + c2 * 16);
  }

  // ---- (1) K/V projection via MFMA ----
  // wave w owns out cols w*32..w*32+31 (w<2: K-dims, w>=2: V-dims), all 64 t-rows.
  f32x4 pacc[4][2] = {};
  {
    const float* xb_ = X + (size_t)b * 4096 * 1024;
    // per-thread staging indices
    const int xrow = tid >> 2, xslot = tid & 3;            // XA: 256 chunks, 1/thread
    for (int kt = 0; kt < 1024; kt += 32) {
      __syncthreads();  // readers of XA/BB done (and 1st iter: harmless)
      // A: 2 float4 -> bf16x8 -> ds_write
      {
        const float* src = xb_ + (size_t)xrow * 1024 + kt + xslot * 8;
        float4 a0 = *(const float4*)src;
        float4 a1 = *(const float4*)(src + 4);
        union { __hip_bfloat16 hh[8]; bf16x8 v; } p;
        p.hh[0] = __float2bfloat16(a0.x); p.hh[1] = __float2bfloat16(a0.y);
        p.hh[2] = __float2bfloat16(a0.z); p.hh[3] = __float2bfloat16(a0.w);
        p.hh[4] = __float2bfloat16(a1.x); p.hh[5] = __float2bfloat16(a1.y);
        p.hh[6] = __float2bfloat16(a1.z); p.hh[7] = __float2bfloat16(a1.w);
        *(bf16x8*)&XA[xrow * 32 + xslot * 8] = p.v;
      }
      // B: 2 gll16/thread (512 chunks); rows<64 -> WkT_h, rows>=64 -> WvT_h
      #pragma unroll
      for (int r = 0; r < 2; ++r) {
        int c = r * 256 + tid;
        int row = c >> 2, slot = c & 3;
        const __hip_bfloat16* src = (row < 64)
            ? WkvT + (size_t)(h * 64 + row) * 1024
            : WkvT + 1048576 + (size_t)(h * 64 + row - 64) * 1024;
        gll16(src + kt + slot * 8, (char*)BB + c * 16);
      }
      __syncthreads();  // drains B gll16 + A ds_writes

      bf16x8 bf0 = *(const bf16x8*)&BB[(w * 32 + lr) * 32 + lk * 8];
      bf16x8 bf1 = *(const bf16x8*)&BB[(w * 32 + 16 + lr) * 32 + lk * 8];
      #pragma unroll
      for (int mi = 0; mi < 4; ++mi) {
        bf16x8 af = *(const bf16x8*)&XA[(mi * 16 + lr) * 32 + lk * 8];
        pacc[mi][0] = __builtin_amdgcn_mfma_f32_16x16x32_bf16(af, bf0, pacc[mi][0], 0, 0, 0);
        pacc[mi][1] = __builtin_amdgcn_mfma_f32_16x16x32_bf16(af, bf1, pacc[mi][1], 0, 0, 0);
      }
    }
  }
  // acc -> Ks / Vs (C-layout: row t = mi*16+lk*4+jj, col = w*32+ni*16+lr; wave-uniform branch)
  #pragma unroll
  for (int mi = 0; mi < 4; ++mi)
    #pragma unroll
    for (int ni = 0; ni < 2; ++ni) {
      int c = w * 32 + ni * 16 + lr;
      #pragma unroll
      for (int jj = 0; jj < 4; ++jj) {
        int t = mi * 16 + lk * 4 + jj;
        if (w < 2) Ks[t][c] = pacc[mi][ni][jj];
        else       Vs[t][c - 64] = pacc[mi][ni][jj];
      }
    }
  __syncthreads();

  // ---- (2) RoPE on Ks: pair pi = tid&31 (fixed per thread), t = (tid>>5) + 8*j ----
  {
    const int pi = tid & 31;
    const float inv = exp2f(-13.287712379549449f * ((float)pi * (1.0f / 32.0f)));
    #pragma unroll
    for (int j = 0; j < 8; ++j) {
      int t = (tid >> 5) + 8 * j;
      float ang = (float)t * inv;
      float s = sinf(ang), c = cosf(ang);
      float k0 = Ks[t][2 * pi], k1 = Ks[t][2 * pi + 1];
      Ks[t][2 * pi]     = k0 * c - k1 * s;
      Ks[t][2 * pi + 1] = k0 * s + k1 * c;
    }
  }
  __syncthreads();

  // ---- (3a) scores: thread = (l = lane, t-chunk = wave) ----
  {
    const int l = tid & 63;
    float q[64];
    const float4* lq4 = (const float4*)(lq + ((size_t)l * 16 + h) * 64);
    #pragma unroll
    for (int i = 0; i < 16; ++i) {
      float4 f = lq4[i];
      q[4 * i] = f.x; q[4 * i + 1] = f.y; q[4 * i + 2] = f.z; q[4 * i + 3] = f.w;
    }
    #pragma unroll
    for (int tl = 0; tl < 16; ++tl) {
      int t = w * 16 + tl;
      float a = 0.f;
      #pragma unroll
      for (int d4 = 0; d4 < 16; ++d4) {
        float4 kf = *(const float4*)&Ks[t][d4 * 4];
        a += q[4 * d4] * kf.x + q[4 * d4 + 1] * kf.y + q[4 * d4 + 2] * kf.z + q[4 * d4 + 3] * kf.w;
      }
      S[l][t] = a * 0.125f;
    }
  }
  __syncthreads();

  // ---- (3b) softmax: thread = (l = tid>>2, c = tid&3), causal t<=l ----
  {
    const int l = tid >> 2, c = tid & 3;
    float sv[16];
    float mx = -3.0e38f;
    #pragma unroll
    for (int i = 0; i < 16; ++i) {
      int t = c * 16 + i;
      sv[i] = S[l][t];
      if (t <= l) mx = fmaxf(mx, sv[i]);
    }
    mx = fmaxf(mx, __shfl_xor(mx, 1));
    mx = fmaxf(mx, __shfl_xor(mx, 2));
    float sum = 0.f;
    float e[16];
    #pragma unroll
    for (int i = 0; i < 16; ++i) {
      int t = c * 16 + i;
      e[i] = (t <= l) ? __expf(sv[i] - mx) : 0.f;
      sum += e[i];
    }
    sum += __shfl_xor(sum, 1);
    sum += __shfl_xor(sum, 2);
    float inv = 1.0f / sum;
    #pragma unroll
    for (int i = 0; i < 16; ++i) Pt[c * 16 + i][l] = e[i] * inv;
  }
  __syncthreads();

  // ---- (3c) PV: thread = (l = lane, d-chunk = wave); ao -> SAo bf16 swizzled ----
  {
    const int l = tid & 63;
    float o[16];
    #pragma unroll
    for (int i = 0; i < 16; ++i) o[i] = 0.f;
    for (int t = 0; t < 64; ++t) {
      float p = Pt[t][l];
      #pragma unroll
      for (int d4 = 0; d4 < 4; ++d4) {
        float4 vf = *(const float4*)&Vs[t][w * 16 + d4 * 4];
        o[4 * d4]     += p * vf.x;
        o[4 * d4 + 1] += p * vf.y;
        o[4 * d4 + 2] += p * vf.z;
        o[4 * d4 + 3] += p * vf.w;
      }
    }
    union { __hip_bfloat16 hh[8]; bf16x8 v; } p0, p1;
    #pragma unroll
    for (int i = 0; i < 8; ++i) { p0.hh[i] = __float2bfloat16(o[i]); p1.hh[i] = __float2bfloat16(o[8 + i]); }
    // logical d-chunks 2w, 2w+1 of row l at physical chunk ^ (l&7)
    *(bf16x8*)&SAo[l * 64 + ((2 * w) ^ (l & 7)) * 8]     = p0.v;
    *(bf16x8*)&SAo[l * 64 + ((2 * w + 1) ^ (l & 7)) * 8] = p1.v;
  }
  __syncthreads();  // drains SAo ds_writes (SW gll16 long done)

  // ---- (4) MFMA: Mt_slice = SW @ SAo^T ----
  f32x4 acc[4][4] = {};
  bf16x8 bfr[2][4];
  #pragma unroll
  for (int kk = 0; kk < 2; ++kk)
    #pragma unroll
    for (int ni = 0; ni < 4; ++ni) {
      int row = ni * 16 + lr;
      int ch = (kk * 4 + lk) ^ (row & 7);
      bfr[kk][ni] = *(const bf16x8*)&SAo[row * 64 + ch * 8];
    }
  #pragma unroll
  for (int mi = 0; mi < 4; ++mi) {
    int row = w * 64 + mi * 16 + lr;
    int ch0 = lk ^ (row & 7);
    int ch1 = (4 + lk) ^ (row & 7);
    bf16x8 a0 = *(const bf16x8*)&SW[row * 64 + ch0 * 8];
    bf16x8 a1 = *(const bf16x8*)&SW[row * 64 + ch1 * 8];
    #pragma unroll
    for (int ni = 0; ni < 4; ++ni)
      acc[mi][ni] = __builtin_amdgcn_mfma_f32_16x16x32_bf16(a0, bfr[0][ni], acc[mi][ni], 0, 0, 0);
    #pragma unroll
    for (int ni = 0; ni < 4; ++ni)
      acc[mi][ni] = __builtin_amdgcn_mfma_f32_16x16x32_bf16(a1, bfr[1][ni], acc[mi][ni], 0, 0, 0);
  }

  // C-layout: row(c) = ct*256 + w*64 + mi*16 + lk*4 + jj, col(l) = ni*16 + lr
  #pragma unroll
  for (int mi = 0; mi < 4; ++mi) {
    int c = ct * 256 + w * 64 + mi * 16 + lk * 4;
    #pragma unroll
    for (int ni = 0; ni < 4; ++ni) {
      int l = ni * 16 + lr;
      #pragma unroll
      for (int jj = 0; jj < 4; ++jj)
        Mt[((size_t)b * 1024 + c + jj) * 1024 + h * 64 + l] = __float2bfloat16(acc[mi][ni][jj]);
    }
  }
}

extern "C" void kernel_launch(void* const* d_in, const int* in_sizes, int n_in,
                              void* d_out, int out_size, void* d_ws, size_t ws_size,
                              hipStream_t stream) {
  const float* x  = (const float*)d_in[0];
  const float* lq = (const float*)d_in[1];
  const float* Wk = (const float*)d_in[2];
  const float* Wv = (const float*)d_in[3];
  const float* Wg = (const float*)d_in[4];
  const float* Wp = (const float*)d_in[5];
  float* out = (float*)d_out;

  // workspace layout (bytes)
  char* w = (char*)d_ws;
  __hip_bfloat16* xb   = (__hip_bfloat16*)(w);              // 33,554,432
  __hip_bfloat16* G    = (__hip_bfloat16*)(w + 33554432);   // 33,554,432
  __hip_bfloat16* WgT  = (__hip_bfloat16*)(w + 67108864);   // 2,097,152
  __hip_bfloat16* WkvT = (__hip_bfloat16*)(w + 69206016);   // 4,194,304
  __hip_bfloat16* WpT  = (__hip_bfloat16*)(w + 73400320);   // 2,097,152
  __hip_bfloat16* Mt   = (__hip_bfloat16*)(w + 75497472);   // 8,388,608
  // total 83,886,080 B

  // x->bf16 + 4 weight transposes, one launch
  prep_kernel<<<6144, 256, 0, stream>>>(x, xb, Wg, Wk, Wv, Wp,
                                        WgT, WkvT, WkvT + 1024 * 1024, WpT);

  // gates: G = softmax_groups(x @ Wg), bf16 [16384,1024] (proven 2-phase)
  gemm256<1><<<dim3(64, 4, 1), 512, 0, stream>>>(xb, WgT, G, 1024, 1024, 0LL, 0LL, 0LL);

  // kv projection + RoPE + attention + Mt build, all in one kernel
  attn_mt<<<dim3(4, 16, 4), 256, 0, stream>>>(x, lq, WkvT, WpT, Mt);

  // out[b] = G[b] @ Mt[b]^T (fp32 out) (proven 2-phase)
  gemm256<0><<<dim3(16, 4, 4), 512, 0, stream>>>(G, Mt, out, 1024, 1024,
                                                 4096LL * 1024, 1024LL * 1024, 4096LL * 1024);
}